// Round 12
// baseline (96.509 us; speedup 1.0000x reference)
//
#include <hip/hip_runtime.h>
#include <hip/hip_bf16.h>
#include <math.h>

#define Bb 4
#define Ss 4096
#define Dd 1024
#define Aa 128
#define NPAIR 528   // per batch: sum_{qb=0}^{31} (qb+1)

typedef __attribute__((ext_vector_type(4))) float f32x4;
typedef __attribute__((ext_vector_type(8))) short bf16x8;

static __device__ __forceinline__ unsigned short f2bf(float f) {
  union { float f; unsigned u; } v; v.f = f;
  unsigned r = v.u + 0x7fffu + ((v.u >> 16) & 1u);
  return (unsigned short)(r >> 16);
}
static __device__ __forceinline__ float bf2f(unsigned short u) {
  union { unsigned u; float f; } v; v.u = ((unsigned)u) << 16;
  return v.f;
}
static __device__ __forceinline__ unsigned int pack2bf(float lo, float hi) {
  return (unsigned int)f2bf(lo) | ((unsigned int)f2bf(hi) << 16);
}
// async global->LDS, 16B per lane: dest = lds_base (wave-uniform) + lane*16
static __device__ __forceinline__ void gload16(const void* g, void* l) {
  __builtin_amdgcn_global_load_lds(
      (const __attribute__((address_space(1))) unsigned int*)g,
      (__attribute__((address_space(3))) unsigned int*)l, 16, 0, 0);
}

// ---------------------------------------------------------------------------
// Kernel 0: Wq/Wk/Wv (fp32 [D][A]) -> FRAGMENT-MAJOR bf16 Wf:
//   Wf[((kc*24 + w*8+nj)*64 + l)*8 + j] = W_w[kc*32 + (l>>4)*8 + j][nj*16 + (l&15)]
// ---------------------------------------------------------------------------
__global__ __launch_bounds__(256) void wconv_kernel(const float* __restrict__ Wq,
    const float* __restrict__ Wk, const float* __restrict__ Wv,
    unsigned short* __restrict__ Wf) {
  const int slot = blockIdx.x * 256 + threadIdx.x;   // 49152 slots
  const int l = slot & 63;
  const int rest = slot >> 6;                        // 0..767
  const int f = rest % 24;
  const int kc = rest / 24;
  const int w = f >> 3, nj = f & 7;
  const float* Wsrc = (w == 0) ? Wq : ((w == 1) ? Wk : Wv);
  const int col = nj * 16 + (l & 15);
  const int krow = kc * 32 + (l >> 4) * 8;
  unsigned short v[8];
#pragma unroll
  for (int j = 0; j < 8; ++j)
    v[j] = f2bf(Wsrc[(size_t)(krow + j) * Aa + col]);
  *reinterpret_cast<int4*>(&Wf[(size_t)slot * 8]) = *reinterpret_cast<const int4*>(v);
}

// ---------------------------------------------------------------------------
// Kernel 1: FUSED QKV projection — 3-deep pipelined GEMM, counted-vmcnt
// barriers (raw s_barrier; async B loads stay in flight ACROSS barriers).
// 512 blocks x 512 thr (8 waves); block = 32 rows of X; BK=32, 32 K-steps.
// B: 3 async global_load_lds per wave into buf[(t+2)%3] (fragment-major,
// linear LDS, conflict-free). A: waves 0-3 reg-stage X (2-deep float4 pipe)
// and ds_write bf16. Waits: stagers keep {3 B + 1 X} newest in flight
// (vmcnt 5/4 by phase), non-stagers keep 3; drain only in the 2-step tail.
// ---------------------------------------------------------------------------
__global__ __launch_bounds__(512) void qkv_kernel(const float* __restrict__ X,
    const unsigned short* __restrict__ Wf,
    unsigned short* __restrict__ Qf, unsigned short* __restrict__ Kf,
    unsigned short* __restrict__ Vf) {
  __shared__ unsigned short Bst[3][12288];   // [buf][24 frags x 64 lanes x 8]
  __shared__ unsigned short Ast[3][1024];    // [buf][2 rg x 64 lanes x 8]
  const int tid = threadIdx.x;
  const int lane = tid & 63;
  const int wid = tid >> 6;
  const int rg = wid >> 2;              // row group for compute
  const int q4 = wid & 3;               // 6-tile quarter
  const int g = lane >> 4, c16 = lane & 15;
  const int mblk = blockIdx.x;          // 32-row tile

  // A staging role (waves 0-3): sl = (rg_s, hf)
  const int sl = tid >> 6;
  const int rg_s = (sl >> 1) & 1, hf = sl & 1;
  const float* Xrow = X + (size_t)(mblk * 32 + rg_s * 16 + c16) * Dd + g * 8 + hf * 4;

  f32x4 acc[6];
  const f32x4 fz = {0.f, 0.f, 0.f, 0.f};
#pragma unroll
  for (int T = 0; T < 6; ++T) acc[T] = fz;

  auto stageB = [&](int dstbuf, int t) {
#pragma unroll
    for (int i = 0; i < 3; ++i) {
      int q = wid * 3 + i;              // fragment 0..23 (wave-uniform)
      gload16(&Wf[((size_t)(t * 24 + q) * 64 + lane) * 8], &Bst[dstbuf][q * 512]);
    }
  };
  auto writeA = [&](int dstbuf, float4 xa) {
    if (tid < 256) {
      ushort4 u;
      u.x = f2bf(xa.x); u.y = f2bf(xa.y); u.z = f2bf(xa.z); u.w = f2bf(xa.w);
      *reinterpret_cast<ushort4*>(&Ast[dstbuf][(rg_s * 64 + lane) * 8 + hf * 4]) = u;
    }
  };

  // prologue: stage 0 and 1; A for 0 written, X for 1,2 in registers
  float4 xaA, xaB;
  stageB(0, 0);
  stageB(1, 1);
  if (tid < 256) {
    float4 x0 = *reinterpret_cast<const float4*>(Xrow);
    writeA(0, x0);
    xaA = *reinterpret_cast<const float4*>(Xrow + 32);
    xaB = *reinterpret_cast<const float4*>(Xrow + 64);
  }
  asm volatile("s_waitcnt vmcnt(0) lgkmcnt(0)" ::: "memory");
  __builtin_amdgcn_s_barrier();
  __builtin_amdgcn_sched_barrier(0);

  int cur = 0;
  for (int t = 0; t < 32; ++t) {
    int nxt1 = cur + 1; if (nxt1 >= 3) nxt1 -= 3;
    int nxt2 = cur + 2; if (nxt2 >= 3) nxt2 -= 3;
    if (t + 2 < 32) stageB(nxt2, t + 2);        // async, stays in flight
    if (t + 1 < 32) { writeA(nxt1, xaA); xaA = xaB; }
    if (tid < 256 && t + 3 < 32)
      xaB = *reinterpret_cast<const float4*>(Xrow + (t + 3) * 32);

    // compute on cur (staged 2 iters ago; readiness ensured by prior barrier)
    bf16x8 af = *reinterpret_cast<const bf16x8*>(&Ast[cur][(rg * 64 + lane) * 8]);
#pragma unroll
    for (int T = 0; T < 6; ++T) {
      int f = q4 * 6 + T;
      bf16x8 bfr = *reinterpret_cast<const bf16x8*>(&Bst[cur][(f * 64 + lane) * 8]);
      acc[T] = __builtin_amdgcn_mfma_f32_16x16x32_bf16(af, bfr, acc[T], 0, 0, 0);
    }

    // counted wait: ensure stage(t+1)/A(t+1) complete, keep stage(t+2) in flight
    if (t <= 28) {
      if (wid < 4) asm volatile("s_waitcnt vmcnt(5) lgkmcnt(0)" ::: "memory");
      else         asm volatile("s_waitcnt vmcnt(3) lgkmcnt(0)" ::: "memory");
    } else if (t == 29) {
      if (wid < 4) asm volatile("s_waitcnt vmcnt(4) lgkmcnt(0)" ::: "memory");
      else         asm volatile("s_waitcnt vmcnt(3) lgkmcnt(0)" ::: "memory");
    } else {
      asm volatile("s_waitcnt vmcnt(0) lgkmcnt(0)" ::: "memory");
    }
    __builtin_amdgcn_s_barrier();
    __builtin_amdgcn_sched_barrier(0);
    cur = nxt1;
  }

  const float qscale = 0.12751744f;  // (1/sqrt(128)) * log2(e)
#pragma unroll
  for (int T = 0; T < 6; ++T) {
    int T2 = q4 * 6 + T;
    int w = T2 >> 3, nj = T2 & 7;
#pragma unroll
    for (int i = 0; i < 4; ++i) {
      int grow = mblk * 32 + rg * 16 + g * 4 + i;
      int n = nj * 16 + c16;
      float val = acc[T][i];
      if (w == 0) {
        val *= qscale;
        int tg = grow >> 4, cr = grow & 15;
        int kk = n >> 5, gq = (n >> 3) & 3, j = n & 7;
        Qf[((tg * 4 + kk) * 64 + gq * 16 + cr) * 8 + j] = f2bf(val);
      } else if (w == 1) {
        int b = grow >> 12, s = grow & 4095;
        int T16 = s >> 4, cr = s & 15;
        int kk = n >> 5, gk = (n >> 3) & 3, j = n & 7;
        Kf[(((b * 256 + T16) * 4 + kk) * 64 + gk * 16 + cr) * 8 + j] = f2bf(val);
      } else {
        int b = grow >> 12, s = grow & 4095;
        int T32 = s >> 5, v32 = s & 31;
        int sg = ((v32 & 15) << 1) | (v32 >> 4);
        int gvn = sg >> 3, jn = sg & 7;
        int nt = n >> 4, cv = n & 15;
        Vf[(((b * 128 + T32) * 8 + nt) * 64 + gvn * 16 + cv) * 8 + jn] = f2bf(val);
      }
    }
  }
}

// ---------------------------------------------------------------------------
// Kernel 2: causal flash attention — LDS-SHARED K/V, equal 2-iteration blocks.
// (unchanged from R10/R11.)
// ---------------------------------------------------------------------------
__global__ __launch_bounds__(512) void attn_kernel(
    const unsigned short* __restrict__ Qf, const unsigned short* __restrict__ Kf,
    const unsigned short* __restrict__ Vf, unsigned int* __restrict__ PartO,
    float* __restrict__ PartL) {
  __shared__ unsigned short Kst[8192];
  __shared__ unsigned short Vst[8192];
  __shared__ unsigned int Psd[8][16][36];
  const int tid = threadIdx.x;
  const int lane = tid & 63;
  const int wid = tid >> 6;
  const int g = lane >> 4, c16 = lane & 15;

  const int bid = blockIdx.x;
  const int xcd = bid & 7;
  const int b = xcd >> 1;
  const int p = xcd & 1;
  const int loc = (bid >> 3) * 2 + p;            // 0..527
  int qb = (int)((sqrtf(8.f * (float)loc + 1.f) - 1.f) * 0.5f);
  while ((qb + 1) * (qb + 2) / 2 <= loc) ++qb;
  while (qb * (qb + 1) / 2 > loc) --qb;
  const int c = loc - qb * (qb + 1) / 2;
  const int idx = b * NPAIR + loc;

  const int qbw = qb * 128 + wid * 16;
  const int tg = b * 256 + qb * 8 + wid;
  bf16x8 qf[4];
#pragma unroll
  for (int kk = 0; kk < 4; ++kk)
    qf[kk] = *reinterpret_cast<const bf16x8*>(&Qf[((size_t)(tg * 4 + kk) * 64 + lane) * 8]);

  const unsigned short* Kb0 = Kf + (size_t)b * 524288;
  const unsigned short* Vb0 = Vf + (size_t)b * 524288;

  const f32x4 fz = {0.f, 0.f, 0.f, 0.f};
  const float FM2 = 17.312340f;
  const float NEG = -1.0e30f;
  f32x4 o[8];
#pragma unroll
  for (int nt = 0; nt < 8; ++nt) o[nt] = fz;
  float lrun[4] = {0.f, 0.f, 0.f, 0.f};

#pragma unroll
  for (int it = 0; it < 2; ++it) {
    if (it) __syncthreads();
    const unsigned short* Ksrc = Kb0 + (size_t)(c * 8 + it * 4) * 2048;
    const unsigned short* Vsrc = Vb0 + (size_t)(c * 4 + it * 2) * 4096;
#pragma unroll
    for (int j = 0; j < 2; ++j) {
      int off = (tid + j * 512) * 8;
      *reinterpret_cast<int4*>(&Kst[off]) = *reinterpret_cast<const int4*>(&Ksrc[off]);
      *reinterpret_cast<int4*>(&Vst[off]) = *reinterpret_cast<const int4*>(&Vsrc[off]);
    }
    __syncthreads();

    const int kv0 = c * 128 + it * 64;
    if (kv0 <= qbw + 15) {
      f32x4 sa[4];
#pragma unroll
      for (int Tl = 0; Tl < 4; ++Tl) {
        sa[Tl] = fz;
        bf16x8 kf[4];
#pragma unroll
        for (int kk = 0; kk < 4; ++kk)
          kf[kk] = *reinterpret_cast<const bf16x8*>(&Kst[((Tl * 4 + kk) * 64 + lane) * 8]);
#pragma unroll
        for (int kk = 0; kk < 4; ++kk)
          sa[Tl] = __builtin_amdgcn_mfma_f32_16x16x32_bf16(qf[kk], kf[kk], sa[Tl], 0, 0, 0);
      }

      const bool need_mask = (kv0 + 63 > qbw);
      float pv[4][4];
#pragma unroll
      for (int i = 0; i < 4; ++i) {
        float v0 = sa[0][i], v1 = sa[1][i], v2 = sa[2][i], v3 = sa[3][i];
        if (need_mask) {
          int qrow = qbw + g * 4 + i;
          if (kv0 + c16 > qrow) v0 = NEG;
          if (kv0 + 16 + c16 > qrow) v1 = NEG;
          if (kv0 + 32 + c16 > qrow) v2 = NEG;
          if (kv0 + 48 + c16 > qrow) v3 = NEG;
        }
        float p0 = exp2f(v0 - FM2);
        float p1 = exp2f(v1 - FM2);
        float p2 = exp2f(v2 - FM2);
        float p3 = exp2f(v3 - FM2);
        lrun[i] += (p0 + p1) + (p2 + p3);
        pv[0][i] = p0; pv[1][i] = p1; pv[2][i] = p2; pv[3][i] = p3;
      }
      unsigned int* Psw = &Psd[wid][0][0];
#pragma unroll
      for (int i = 0; i < 4; ++i) {
        Psw[(4 * g + i) * 36 + c16] = pack2bf(pv[0][i], pv[1][i]);
        Psw[(4 * g + i) * 36 + 16 + c16] = pack2bf(pv[2][i], pv[3][i]);
      }
      bf16x8 pf0 = *reinterpret_cast<const bf16x8*>(&Psw[c16 * 36 + 4 * g]);
      bf16x8 pf1 = *reinterpret_cast<const bf16x8*>(&Psw[c16 * 36 + 16 + 4 * g]);
#pragma unroll
      for (int nt = 0; nt < 8; ++nt) {
        bf16x8 vf = *reinterpret_cast<const bf16x8*>(&Vst[(nt * 64 + lane) * 8]);
        o[nt] = __builtin_amdgcn_mfma_f32_16x16x32_bf16(pf0, vf, o[nt], 0, 0, 0);
      }
#pragma unroll
      for (int nt = 0; nt < 8; ++nt) {
        bf16x8 vf = *reinterpret_cast<const bf16x8*>(&Vst[((8 + nt) * 64 + lane) * 8]);
        o[nt] = __builtin_amdgcn_mfma_f32_16x16x32_bf16(pf1, vf, o[nt], 0, 0, 0);
      }
    }
  }

#pragma unroll
  for (int i = 0; i < 4; ++i) {
    float l = lrun[i];
#pragma unroll
    for (int msk = 1; msk <= 8; msk <<= 1) l += __shfl_xor(l, msk);
    lrun[i] = l;
  }
  if (c16 == 0) {
#pragma unroll
    for (int i = 0; i < 4; ++i)
      PartL[(size_t)idx * 128 + wid * 16 + g * 4 + i] = lrun[i];
  }
#pragma unroll
  for (int qd = 0; qd < 4; ++qd)
#pragma unroll
    for (int i = 0; i < 4; ++i)
      PartO[(size_t)idx * 8192 + (wid * 16 + g * 4 + i) * 64 + qd * 16 + c16] =
          pack2bf(o[2 * qd][i], o[2 * qd + 1][i]);
}

// ---------------------------------------------------------------------------
// Kernel 3: combine partials (unchanged).
// ---------------------------------------------------------------------------
__global__ __launch_bounds__(512) void combine_kernel(
    const unsigned int* __restrict__ PartO, const float* __restrict__ PartL,
    float* __restrict__ out) {
  const int bid = blockIdx.x;
  const int b = bid >> 7;
  const int sub = bid & 127;
  const int qb = sub >> 2;
  const int rq = sub & 3;
  const int tid = threadIdx.x;
  const int r = rq * 32 + (tid >> 4);
  const int dwb = (tid & 15) * 4;
  const int base = b * NPAIR + qb * (qb + 1) / 2;

  float accLo[4] = {0.f, 0.f, 0.f, 0.f};
  float accHi[4] = {0.f, 0.f, 0.f, 0.f};
  float l = 0.f;
  for (int c = 0; c <= qb; ++c) {
    const int idx = base + c;
    l += PartL[(size_t)idx * 128 + r];
    const uint4 d = *reinterpret_cast<const uint4*>(
        &PartO[(size_t)idx * 8192 + r * 64 + dwb]);
    accLo[0] += bf2f((unsigned short)(d.x & 0xffff)); accHi[0] += bf2f((unsigned short)(d.x >> 16));
    accLo[1] += bf2f((unsigned short)(d.y & 0xffff)); accHi[1] += bf2f((unsigned short)(d.y >> 16));
    accLo[2] += bf2f((unsigned short)(d.z & 0xffff)); accHi[2] += bf2f((unsigned short)(d.z >> 16));
    accLo[3] += bf2f((unsigned short)(d.w & 0xffff)); accHi[3] += bf2f((unsigned short)(d.w >> 16));
  }
  const float inv = 1.0f / l;
  const size_t rowoff = ((size_t)b * Ss + qb * 128 + r) * Aa;
#pragma unroll
  for (int u = 0; u < 4; ++u) {
    int d = dwb + u;
    int colA = (d >> 4) * 32 + (d & 15);
    out[rowoff + colA] = rintf(accLo[u] * inv * 1e4f) * 1e-4f;
    out[rowoff + colA + 16] = rintf(accHi[u] * inv * 1e4f) * 1e-4f;
  }
}

// ---------------------------------------------------------------------------
extern "C" void kernel_launch(void* const* d_in, const int* in_sizes, int n_in,
                              void* d_out, int out_size, void* d_ws, size_t ws_size,
                              hipStream_t stream) {
  const float* X  = (const float*)d_in[0];
  const float* Wq = (const float*)d_in[1];
  const float* Wk = (const float*)d_in[2];
  const float* Wv = (const float*)d_in[3];
  float* out = (float*)d_out;

  unsigned char* ws = (unsigned char*)d_ws;
  unsigned short* Qf = (unsigned short*)(ws);                  // 4 MB fragment-major
  unsigned short* Kf = (unsigned short*)(ws + 4194304);        // 4 MB
  unsigned short* Vf = (unsigned short*)(ws + 8388608);        // 4 MB (kv-slot permuted)
  unsigned short* Wf = (unsigned short*)(ws + 12582912);       // 768 KB fragment-major
  unsigned int*  PartO = (unsigned int*)(ws + 13631488);       // 69.2 MB packed bf16
  float*         PartL = (float*)(ws + 82837504);              // 1.08 MB

  hipLaunchKernelGGL(wconv_kernel, dim3(192), dim3(256), 0, stream, Wq, Wk, Wv, Wf);
  hipLaunchKernelGGL(qkv_kernel, dim3(512), dim3(512), 0, stream, X, Wf, Qf, Kf, Vf);
  hipLaunchKernelGGL(attn_kernel, dim3(2112), dim3(512), 0, stream, Qf, Kf, Vf, PartO, PartL);
  hipLaunchKernelGGL(combine_kernel, dim3(512), dim3(512), 0, stream, PartO, PartL, out);
}

// Round 13
// 89.102 us; speedup vs baseline: 1.0831x; 1.0831x over previous
//
#include <hip/hip_runtime.h>
#include <hip/hip_bf16.h>
#include <math.h>

#define Bb 4
#define Ss 4096
#define Dd 1024
#define Aa 128
#define NPAIR 272   // per batch: sum_{qb=0}^{31} ceil((qb+1)/2)

typedef __attribute__((ext_vector_type(4))) float f32x4;
typedef __attribute__((ext_vector_type(8))) short bf16x8;

static __device__ __forceinline__ unsigned short f2bf(float f) {
  union { float f; unsigned u; } v; v.f = f;
  unsigned r = v.u + 0x7fffu + ((v.u >> 16) & 1u);
  return (unsigned short)(r >> 16);
}
static __device__ __forceinline__ float bf2f(unsigned short u) {
  union { unsigned u; float f; } v; v.u = ((unsigned)u) << 16;
  return v.f;
}
static __device__ __forceinline__ unsigned int pack2bf(float lo, float hi) {
  return (unsigned int)f2bf(lo) | ((unsigned int)f2bf(hi) << 16);
}
// async global->LDS, 16B per lane: dest = lds_base (wave-uniform) + lane*16
static __device__ __forceinline__ void gload16(const void* g, void* l) {
  __builtin_amdgcn_global_load_lds(
      (const __attribute__((address_space(1))) unsigned int*)g,
      (__attribute__((address_space(3))) unsigned int*)l, 16, 0, 0);
}

// ---------------------------------------------------------------------------
// Kernel 0: Wq/Wk/Wv (fp32 [D][A]) -> FRAGMENT-MAJOR bf16 Wf:
//   Wf[((kc*24 + w*8+nj)*64 + l)*8 + j] = W_w[kc*32 + (l>>4)*8 + j][nj*16 + (l&15)]
// ---------------------------------------------------------------------------
__global__ __launch_bounds__(256) void wconv_kernel(const float* __restrict__ Wq,
    const float* __restrict__ Wk, const float* __restrict__ Wv,
    unsigned short* __restrict__ Wf) {
  const int slot = blockIdx.x * 256 + threadIdx.x;   // 49152 slots
  const int l = slot & 63;
  const int rest = slot >> 6;                        // 0..767
  const int f = rest % 24;
  const int kc = rest / 24;
  const int w = f >> 3, nj = f & 7;
  const float* Wsrc = (w == 0) ? Wq : ((w == 1) ? Wk : Wv);
  const int col = nj * 16 + (l & 15);
  const int krow = kc * 32 + (l >> 4) * 8;
  unsigned short v[8];
#pragma unroll
  for (int j = 0; j < 8; ++j)
    v[j] = f2bf(Wsrc[(size_t)(krow + j) * Aa + col]);
  *reinterpret_cast<int4*>(&Wf[(size_t)slot * 8]) = *reinterpret_cast<const int4*>(v);
}

// ---------------------------------------------------------------------------
// Kernel 1: QKV projection — m97 geometry. Grid (128, 3): block = 128 rows x
// one W matrix (128 cols). 256 thr = 4 waves (2x2), wave = 64x64, acc 4x4.
// BK=64, 16 K-steps; per step: A reg-staged (8 float4/thread, cvt, ds_write
// to [128][72]); B via 16 global_load_lds (fragment-major, linear LDS).
// Per wave per step: 16 MFMA : 8 ds_read_b128 (the measured-874TF ratio).
// Q pre-scaled by (1/sqrt(A))*log2(e); V kv-slot permuted; frag-major outs.
// ---------------------------------------------------------------------------
__global__ __launch_bounds__(256) void qkv_kernel(const float* __restrict__ X,
    const unsigned short* __restrict__ Wf,
    unsigned short* __restrict__ Qf, unsigned short* __restrict__ Kf,
    unsigned short* __restrict__ Vf) {
  __shared__ unsigned short As[128][72];     // [m][k], +8 pad
  __shared__ unsigned short Bst[8192];       // 16 frags x 64 lanes x 8 bf16
  const int tid = threadIdx.x;
  const int lane = tid & 63;
  const int wid = tid >> 6;
  const int wr = wid >> 1, wc = wid & 1;
  const int g = lane >> 4, r16 = lane & 15;
  const int mblk = blockIdx.x;               // 128-row tile, 0..127
  const int w = blockIdx.y;                  // 0=Q 1=K 2=V

  f32x4 acc[4][4];
  const f32x4 fz = {0.f, 0.f, 0.f, 0.f};
#pragma unroll
  for (int mi = 0; mi < 4; ++mi)
#pragma unroll
    for (int nj = 0; nj < 4; ++nj) acc[mi][nj] = fz;

  for (int t = 0; t < 16; ++t) {
    // stage B: 4 fragments per wave, async (16 total = 16KB)
#pragma unroll
    for (int fi = 0; fi < 4; ++fi) {
      int f = wid * 4 + fi;                  // kcl = f>>3, njg = f&7
      gload16(&Wf[((size_t)((2 * t + (f >> 3)) * 24 + w * 8 + (f & 7)) * 64 + lane) * 8],
              &Bst[f * 512]);
    }
    // stage A: 128x64 fp32 -> bf16 (8 float4/thread)
#pragma unroll
    for (int i = 0; i < 8; ++i) {
      int slot = tid + i * 256;
      int r = slot >> 4;
      int c4 = (slot & 15) << 2;
      const float4 v = *reinterpret_cast<const float4*>(
          &X[(size_t)(mblk * 128 + r) * Dd + t * 64 + c4]);
      ushort4 u;
      u.x = f2bf(v.x); u.y = f2bf(v.y); u.z = f2bf(v.z); u.w = f2bf(v.w);
      *reinterpret_cast<ushort4*>(&As[r][c4]) = u;
    }
    __syncthreads();
#pragma unroll
    for (int ks = 0; ks < 2; ++ks) {
      bf16x8 a[4], b[4];
#pragma unroll
      for (int mi = 0; mi < 4; ++mi)
        a[mi] = *reinterpret_cast<const bf16x8*>(&As[wr * 64 + mi * 16 + r16][ks * 32 + g * 8]);
#pragma unroll
      for (int nj = 0; nj < 4; ++nj)
        b[nj] = *reinterpret_cast<const bf16x8*>(&Bst[((ks * 8 + wc * 4 + nj) * 64 + lane) * 8]);
#pragma unroll
      for (int mi = 0; mi < 4; ++mi)
#pragma unroll
        for (int nj = 0; nj < 4; ++nj)
          acc[mi][nj] = __builtin_amdgcn_mfma_f32_16x16x32_bf16(a[mi], b[nj], acc[mi][nj], 0, 0, 0);
    }
    __syncthreads();
  }

  const float qscale = 0.12751744f;  // (1/sqrt(128)) * log2(e)
#pragma unroll
  for (int mi = 0; mi < 4; ++mi) {
#pragma unroll
    for (int nj = 0; nj < 4; ++nj) {
#pragma unroll
      for (int i = 0; i < 4; ++i) {
        int m = wr * 64 + mi * 16 + g * 4 + i;
        int n = wc * 64 + nj * 16 + r16;
        int grow = mblk * 128 + m;
        float val = acc[mi][nj][i];
        if (w == 0) {
          val *= qscale;
          int tg = grow >> 4, cr = grow & 15;
          int kk = n >> 5, gq = (n >> 3) & 3, j = n & 7;
          Qf[((tg * 4 + kk) * 64 + gq * 16 + cr) * 8 + j] = f2bf(val);
        } else if (w == 1) {
          int b = grow >> 12, s = grow & 4095;
          int T16 = s >> 4, cr = s & 15;
          int kk = n >> 5, gk = (n >> 3) & 3, j = n & 7;
          Kf[(((b * 256 + T16) * 4 + kk) * 64 + gk * 16 + cr) * 8 + j] = f2bf(val);
        } else {
          int b = grow >> 12, s = grow & 4095;
          int T32 = s >> 5, v32 = s & 31;
          int sg = ((v32 & 15) << 1) | (v32 >> 4);   // permuted kv slot
          int gvn = sg >> 3, jn = sg & 7;
          int nt = n >> 4, cv = n & 15;
          Vf[(((b * 128 + T32) * 8 + nt) * 64 + gvn * 16 + cv) * 8 + jn] = f2bf(val);
        }
      }
    }
  }
}

// ---------------------------------------------------------------------------
// Kernel 2: causal flash attention — LDS-shared K/V, 4-iteration blocks.
// Block = (b, qb: 128 q-rows, kv-chunk c of 256 kv); iterates 4 KVBLK=64
// tiles. 8 waves x 16 q-rows share staged K/V. Fixed-max softmax
// exp2(s'-12log2e); partial O (packed bf16) + L summed by combiner.
// Chunks per qb = ceil((qb+1)/2); S(qb) = floor((qb+1)^2/4); 272/batch.
// ---------------------------------------------------------------------------
__global__ __launch_bounds__(512) void attn_kernel(
    const unsigned short* __restrict__ Qf, const unsigned short* __restrict__ Kf,
    const unsigned short* __restrict__ Vf, unsigned int* __restrict__ PartO,
    float* __restrict__ PartL) {
  __shared__ unsigned short Kst[8192];
  __shared__ unsigned short Vst[8192];
  __shared__ unsigned int Psd[8][16][36];
  const int tid = threadIdx.x;
  const int lane = tid & 63;
  const int wid = tid >> 6;
  const int g = lane >> 4, c16 = lane & 15;

  const int bid = blockIdx.x;                    // 1088 blocks = 8 * 136
  const int xcd = bid & 7;
  const int b = xcd >> 1;
  const int p = xcd & 1;
  const int loc = (bid >> 3) * 2 + p;            // 0..271
  // invert S(qb) = floor((qb+1)^2/4)
  int qb = (int)(2.0f * sqrtf((float)loc + 1.0f));
  if (qb > 31) qb = 31;
  while (qb > 0 && ((qb + 1) * (qb + 1)) / 4 > loc) --qb;
  while (qb < 31 && ((qb + 2) * (qb + 2)) / 4 <= loc) ++qb;
  const int c = loc - ((qb + 1) * (qb + 1)) / 4; // chunk 0..ceil((qb+1)/2)-1
  const int idx = b * NPAIR + loc;

  const int qbw = qb * 128 + wid * 16;
  const int tg = b * 256 + qb * 8 + wid;
  bf16x8 qf[4];
#pragma unroll
  for (int kk = 0; kk < 4; ++kk)
    qf[kk] = *reinterpret_cast<const bf16x8*>(&Qf[((size_t)(tg * 4 + kk) * 64 + lane) * 8]);

  const unsigned short* Kb0 = Kf + (size_t)b * 524288;
  const unsigned short* Vb0 = Vf + (size_t)b * 524288;

  const f32x4 fz = {0.f, 0.f, 0.f, 0.f};
  const float FM2 = 17.312340f;
  const float NEG = -1.0e30f;
  f32x4 o[8];
#pragma unroll
  for (int nt = 0; nt < 8; ++nt) o[nt] = fz;
  float lrun[4] = {0.f, 0.f, 0.f, 0.f};

#pragma unroll
  for (int it = 0; it < 4; ++it) {
    if (it) __syncthreads();
    const unsigned short* Ksrc = Kb0 + (size_t)(c * 16 + it * 4) * 2048;
    const unsigned short* Vsrc = Vb0 + (size_t)(c * 8 + it * 2) * 4096;
#pragma unroll
    for (int j = 0; j < 2; ++j) {
      int off = (tid + j * 512) * 8;
      *reinterpret_cast<int4*>(&Kst[off]) = *reinterpret_cast<const int4*>(&Ksrc[off]);
      *reinterpret_cast<int4*>(&Vst[off]) = *reinterpret_cast<const int4*>(&Vsrc[off]);
    }
    __syncthreads();

    const int kv0 = c * 256 + it * 64;
    if (kv0 <= qbw + 15) {
      f32x4 sa[4];
#pragma unroll
      for (int Tl = 0; Tl < 4; ++Tl) {
        sa[Tl] = fz;
        bf16x8 kf[4];
#pragma unroll
        for (int kk = 0; kk < 4; ++kk)
          kf[kk] = *reinterpret_cast<const bf16x8*>(&Kst[((Tl * 4 + kk) * 64 + lane) * 8]);
#pragma unroll
        for (int kk = 0; kk < 4; ++kk)
          sa[Tl] = __builtin_amdgcn_mfma_f32_16x16x32_bf16(qf[kk], kf[kk], sa[Tl], 0, 0, 0);
      }

      const bool need_mask = (kv0 + 63 > qbw);
      float pv[4][4];
#pragma unroll
      for (int i = 0; i < 4; ++i) {
        float v0 = sa[0][i], v1 = sa[1][i], v2 = sa[2][i], v3 = sa[3][i];
        if (need_mask) {
          int qrow = qbw + g * 4 + i;
          if (kv0 + c16 > qrow) v0 = NEG;
          if (kv0 + 16 + c16 > qrow) v1 = NEG;
          if (kv0 + 32 + c16 > qrow) v2 = NEG;
          if (kv0 + 48 + c16 > qrow) v3 = NEG;
        }
        float p0 = exp2f(v0 - FM2);
        float p1 = exp2f(v1 - FM2);
        float p2 = exp2f(v2 - FM2);
        float p3 = exp2f(v3 - FM2);
        lrun[i] += (p0 + p1) + (p2 + p3);
        pv[0][i] = p0; pv[1][i] = p1; pv[2][i] = p2; pv[3][i] = p3;
      }
      unsigned int* Psw = &Psd[wid][0][0];
#pragma unroll
      for (int i = 0; i < 4; ++i) {
        Psw[(4 * g + i) * 36 + c16] = pack2bf(pv[0][i], pv[1][i]);
        Psw[(4 * g + i) * 36 + 16 + c16] = pack2bf(pv[2][i], pv[3][i]);
      }
      bf16x8 pf0 = *reinterpret_cast<const bf16x8*>(&Psw[c16 * 36 + 4 * g]);
      bf16x8 pf1 = *reinterpret_cast<const bf16x8*>(&Psw[c16 * 36 + 16 + 4 * g]);
#pragma unroll
      for (int nt = 0; nt < 8; ++nt) {
        bf16x8 vf = *reinterpret_cast<const bf16x8*>(&Vst[(nt * 64 + lane) * 8]);
        o[nt] = __builtin_amdgcn_mfma_f32_16x16x32_bf16(pf0, vf, o[nt], 0, 0, 0);
      }
#pragma unroll
      for (int nt = 0; nt < 8; ++nt) {
        bf16x8 vf = *reinterpret_cast<const bf16x8*>(&Vst[((8 + nt) * 64 + lane) * 8]);
        o[nt] = __builtin_amdgcn_mfma_f32_16x16x32_bf16(pf1, vf, o[nt], 0, 0, 0);
      }
    }
  }

#pragma unroll
  for (int i = 0; i < 4; ++i) {
    float l = lrun[i];
#pragma unroll
    for (int msk = 1; msk <= 8; msk <<= 1) l += __shfl_xor(l, msk);
    lrun[i] = l;
  }
  if (c16 == 0) {
#pragma unroll
    for (int i = 0; i < 4; ++i)
      PartL[(size_t)idx * 128 + wid * 16 + g * 4 + i] = lrun[i];
  }
#pragma unroll
  for (int qd = 0; qd < 4; ++qd)
#pragma unroll
    for (int i = 0; i < 4; ++i)
      PartO[(size_t)idx * 8192 + (wid * 16 + g * 4 + i) * 64 + qd * 16 + c16] =
          pack2bf(o[2 * qd][i], o[2 * qd + 1][i]);
}

// ---------------------------------------------------------------------------
// Kernel 3: combine partials. 512 blocks x 512 thr. Block: (b, qb, row-quarter).
// Sums ceil((qb+1)/2) chunks, divides by L, rounds, stores.
// ---------------------------------------------------------------------------
__global__ __launch_bounds__(512) void combine_kernel(
    const unsigned int* __restrict__ PartO, const float* __restrict__ PartL,
    float* __restrict__ out) {
  const int bid = blockIdx.x;
  const int b = bid >> 7;
  const int sub = bid & 127;
  const int qb = sub >> 2;
  const int rq = sub & 3;
  const int tid = threadIdx.x;
  const int r = rq * 32 + (tid >> 4);
  const int dwb = (tid & 15) * 4;
  const int base = b * NPAIR + ((qb + 1) * (qb + 1)) / 4;
  const int nch = (qb + 2) >> 1;

  float accLo[4] = {0.f, 0.f, 0.f, 0.f};
  float accHi[4] = {0.f, 0.f, 0.f, 0.f};
  float l = 0.f;
  for (int c = 0; c < nch; ++c) {
    const int idx = base + c;
    l += PartL[(size_t)idx * 128 + r];
    const uint4 d = *reinterpret_cast<const uint4*>(
        &PartO[(size_t)idx * 8192 + r * 64 + dwb]);
    accLo[0] += bf2f((unsigned short)(d.x & 0xffff)); accHi[0] += bf2f((unsigned short)(d.x >> 16));
    accLo[1] += bf2f((unsigned short)(d.y & 0xffff)); accHi[1] += bf2f((unsigned short)(d.y >> 16));
    accLo[2] += bf2f((unsigned short)(d.z & 0xffff)); accHi[2] += bf2f((unsigned short)(d.z >> 16));
    accLo[3] += bf2f((unsigned short)(d.w & 0xffff)); accHi[3] += bf2f((unsigned short)(d.w >> 16));
  }
  const float inv = 1.0f / l;
  const size_t rowoff = ((size_t)b * Ss + qb * 128 + r) * Aa;
#pragma unroll
  for (int u = 0; u < 4; ++u) {
    int d = dwb + u;
    int colA = (d >> 4) * 32 + (d & 15);
    out[rowoff + colA] = rintf(accLo[u] * inv * 1e4f) * 1e-4f;
    out[rowoff + colA + 16] = rintf(accHi[u] * inv * 1e4f) * 1e-4f;
  }
}

// ---------------------------------------------------------------------------
extern "C" void kernel_launch(void* const* d_in, const int* in_sizes, int n_in,
                              void* d_out, int out_size, void* d_ws, size_t ws_size,
                              hipStream_t stream) {
  const float* X  = (const float*)d_in[0];
  const float* Wq = (const float*)d_in[1];
  const float* Wk = (const float*)d_in[2];
  const float* Wv = (const float*)d_in[3];
  float* out = (float*)d_out;

  unsigned char* ws = (unsigned char*)d_ws;
  unsigned short* Qf = (unsigned short*)(ws);                  // 4 MB fragment-major
  unsigned short* Kf = (unsigned short*)(ws + 4194304);        // 4 MB
  unsigned short* Vf = (unsigned short*)(ws + 8388608);        // 4 MB (kv-slot permuted)
  unsigned short* Wf = (unsigned short*)(ws + 12582912);       // 768 KB fragment-major
  unsigned int*  PartO = (unsigned int*)(ws + 13631488);       // 35.7 MB packed bf16
  float*         PartL = (float*)(ws + 49283072);              // 557 KB

  hipLaunchKernelGGL(wconv_kernel, dim3(192), dim3(256), 0, stream, Wq, Wk, Wv, Wf);
  hipLaunchKernelGGL(qkv_kernel, dim3(128, 3), dim3(256), 0, stream, X, Wf, Qf, Kf, Vf);
  hipLaunchKernelGGL(attn_kernel, dim3(1088), dim3(512), 0, stream, Qf, Kf, Vf, PartO, PartL);
  hipLaunchKernelGGL(combine_kernel, dim3(512), dim3(512), 0, stream, PartO, PartL, out);
}

// Round 14
// 80.795 us; speedup vs baseline: 1.1945x; 1.1028x over previous
//
#include <hip/hip_runtime.h>
#include <hip/hip_bf16.h>
#include <math.h>

#define Bb 4
#define Ss 4096
#define Dd 1024
#define Aa 128
#define NPAIR 272   // per batch: sum_{qb=0}^{31} ceil((qb+1)/2)

typedef __attribute__((ext_vector_type(4))) float f32x4;
typedef __attribute__((ext_vector_type(8))) short bf16x8;

static __device__ __forceinline__ unsigned short f2bf(float f) {
  union { float f; unsigned u; } v; v.f = f;
  unsigned r = v.u + 0x7fffu + ((v.u >> 16) & 1u);
  return (unsigned short)(r >> 16);
}
static __device__ __forceinline__ float bf2f(unsigned short u) {
  union { unsigned u; float f; } v; v.u = ((unsigned)u) << 16;
  return v.f;
}
static __device__ __forceinline__ unsigned int pack2bf(float lo, float hi) {
  return (unsigned int)f2bf(lo) | ((unsigned int)f2bf(hi) << 16);
}
// async global->LDS, 16B per lane: dest = lds_base (wave-uniform) + lane*16
static __device__ __forceinline__ void gload16(const void* g, void* l) {
  __builtin_amdgcn_global_load_lds(
      (const __attribute__((address_space(1))) unsigned int*)g,
      (__attribute__((address_space(3))) unsigned int*)l, 16, 0, 0);
}

// ---------------------------------------------------------------------------
// Kernel 0: Wq/Wk/Wv (fp32 [D][A]) -> FRAGMENT-MAJOR bf16 Wf:
//   Wf[((kc*24 + w*8+nj)*64 + l)*8 + j] = W_w[kc*32 + (l>>4)*8 + j][nj*16 + (l&15)]
// ---------------------------------------------------------------------------
__global__ __launch_bounds__(256) void wconv_kernel(const float* __restrict__ Wq,
    const float* __restrict__ Wk, const float* __restrict__ Wv,
    unsigned short* __restrict__ Wf) {
  const int slot = blockIdx.x * 256 + threadIdx.x;   // 49152 slots
  const int l = slot & 63;
  const int rest = slot >> 6;                        // 0..767
  const int f = rest % 24;
  const int kc = rest / 24;
  const int w = f >> 3, nj = f & 7;
  const float* Wsrc = (w == 0) ? Wq : ((w == 1) ? Wk : Wv);
  const int col = nj * 16 + (l & 15);
  const int krow = kc * 32 + (l >> 4) * 8;
  unsigned short v[8];
#pragma unroll
  for (int j = 0; j < 8; ++j)
    v[j] = f2bf(Wsrc[(size_t)(krow + j) * Aa + col]);
  *reinterpret_cast<int4*>(&Wf[(size_t)slot * 8]) = *reinterpret_cast<const int4*>(v);
}

// ---------------------------------------------------------------------------
// Kernel 1: QKV projection — m97 structure at OCCUPANCY-FIXED grid.
// BM=64, BN=128, BK=64, 16 K-steps. Grid (256, 3) = 768 blocks = exactly
// 3 blocks/CU (equal length), 256 thr = 4 waves (2x2; wave = 32 rows x 64
// cols, acc[2][4]). LDS 25 KB -> 3 blocks co-resident; implicit wave-level
// overlap (m114) hides the 2-barrier staging drain. B via global_load_lds
// (fragment-major, linear LDS); A reg-staged fp32->bf16.
// ---------------------------------------------------------------------------
__global__ __launch_bounds__(256) void qkv_kernel(const float* __restrict__ X,
    const unsigned short* __restrict__ Wf,
    unsigned short* __restrict__ Qf, unsigned short* __restrict__ Kf,
    unsigned short* __restrict__ Vf) {
  __shared__ unsigned short As[64][72];      // [m][k], +8 pad (9.2 KB)
  __shared__ unsigned short Bst[8192];       // 16 frags x 64 lanes x 8 bf16 (16 KB)
  const int tid = threadIdx.x;
  const int lane = tid & 63;
  const int wid = tid >> 6;
  const int wr = wid >> 1, wc = wid & 1;     // wave = 32 rows x 64 cols
  const int g = lane >> 4, r16 = lane & 15;
  const int mblk = blockIdx.x;               // 64-row tile, 0..255
  const int w = blockIdx.y;                  // 0=Q 1=K 2=V

  f32x4 acc[2][4];
  const f32x4 fz = {0.f, 0.f, 0.f, 0.f};
#pragma unroll
  for (int mi = 0; mi < 2; ++mi)
#pragma unroll
    for (int nj = 0; nj < 4; ++nj) acc[mi][nj] = fz;

  for (int t = 0; t < 16; ++t) {
    // stage B: 4 fragments per wave, async (16 total = 16KB)
#pragma unroll
    for (int fi = 0; fi < 4; ++fi) {
      int f = wid * 4 + fi;                  // kc-half = f>>3, nj-group = f&7
      gload16(&Wf[((size_t)((2 * t + (f >> 3)) * 24 + w * 8 + (f & 7)) * 64 + lane) * 8],
              &Bst[f * 512]);
    }
    // stage A: 64x64 fp32 -> bf16 (4 float4/thread)
#pragma unroll
    for (int i = 0; i < 4; ++i) {
      int slot = tid + i * 256;
      int r = slot >> 4;
      int c4 = (slot & 15) << 2;
      const float4 v = *reinterpret_cast<const float4*>(
          &X[(size_t)(mblk * 64 + r) * Dd + t * 64 + c4]);
      ushort4 u;
      u.x = f2bf(v.x); u.y = f2bf(v.y); u.z = f2bf(v.z); u.w = f2bf(v.w);
      *reinterpret_cast<ushort4*>(&As[r][c4]) = u;
    }
    __syncthreads();
#pragma unroll
    for (int ks = 0; ks < 2; ++ks) {
      bf16x8 a[2], b[4];
#pragma unroll
      for (int mi = 0; mi < 2; ++mi)
        a[mi] = *reinterpret_cast<const bf16x8*>(&As[wr * 32 + mi * 16 + r16][ks * 32 + g * 8]);
#pragma unroll
      for (int nj = 0; nj < 4; ++nj)
        b[nj] = *reinterpret_cast<const bf16x8*>(&Bst[((ks * 8 + wc * 4 + nj) * 64 + lane) * 8]);
#pragma unroll
      for (int mi = 0; mi < 2; ++mi)
#pragma unroll
        for (int nj = 0; nj < 4; ++nj)
          acc[mi][nj] = __builtin_amdgcn_mfma_f32_16x16x32_bf16(a[mi], b[nj], acc[mi][nj], 0, 0, 0);
    }
    __syncthreads();
  }

  const float qscale = 0.12751744f;  // (1/sqrt(128)) * log2(e)
#pragma unroll
  for (int mi = 0; mi < 2; ++mi) {
#pragma unroll
    for (int nj = 0; nj < 4; ++nj) {
#pragma unroll
      for (int i = 0; i < 4; ++i) {
        int m = wr * 32 + mi * 16 + g * 4 + i;
        int n = wc * 64 + nj * 16 + r16;
        int grow = mblk * 64 + m;
        float val = acc[mi][nj][i];
        if (w == 0) {
          val *= qscale;
          int tg = grow >> 4, cr = grow & 15;
          int kk = n >> 5, gq = (n >> 3) & 3, j = n & 7;
          Qf[((tg * 4 + kk) * 64 + gq * 16 + cr) * 8 + j] = f2bf(val);
        } else if (w == 1) {
          int b = grow >> 12, s = grow & 4095;
          int T16 = s >> 4, cr = s & 15;
          int kk = n >> 5, gk = (n >> 3) & 3, j = n & 7;
          Kf[(((b * 256 + T16) * 4 + kk) * 64 + gk * 16 + cr) * 8 + j] = f2bf(val);
        } else {
          int b = grow >> 12, s = grow & 4095;
          int T32 = s >> 5, v32 = s & 31;
          int sg = ((v32 & 15) << 1) | (v32 >> 4);   // permuted kv slot
          int gvn = sg >> 3, jn = sg & 7;
          int nt = n >> 4, cv = n & 15;
          Vf[(((b * 128 + T32) * 8 + nt) * 64 + gvn * 16 + cv) * 8 + jn] = f2bf(val);
        }
      }
    }
  }
}

// ---------------------------------------------------------------------------
// Kernel 2: causal flash attention — LDS-shared K/V, 4-iteration blocks.
// (unchanged from R13.)
// ---------------------------------------------------------------------------
__global__ __launch_bounds__(512) void attn_kernel(
    const unsigned short* __restrict__ Qf, const unsigned short* __restrict__ Kf,
    const unsigned short* __restrict__ Vf, unsigned int* __restrict__ PartO,
    float* __restrict__ PartL) {
  __shared__ unsigned short Kst[8192];
  __shared__ unsigned short Vst[8192];
  __shared__ unsigned int Psd[8][16][36];
  const int tid = threadIdx.x;
  const int lane = tid & 63;
  const int wid = tid >> 6;
  const int g = lane >> 4, c16 = lane & 15;

  const int bid = blockIdx.x;                    // 1088 blocks = 8 * 136
  const int xcd = bid & 7;
  const int b = xcd >> 1;
  const int p = xcd & 1;
  const int loc = (bid >> 3) * 2 + p;            // 0..271
  int qb = (int)(2.0f * sqrtf((float)loc + 1.0f));
  if (qb > 31) qb = 31;
  while (qb > 0 && ((qb + 1) * (qb + 1)) / 4 > loc) --qb;
  while (qb < 31 && ((qb + 2) * (qb + 2)) / 4 <= loc) ++qb;
  const int c = loc - ((qb + 1) * (qb + 1)) / 4;
  const int idx = b * NPAIR + loc;

  const int qbw = qb * 128 + wid * 16;
  const int tg = b * 256 + qb * 8 + wid;
  bf16x8 qf[4];
#pragma unroll
  for (int kk = 0; kk < 4; ++kk)
    qf[kk] = *reinterpret_cast<const bf16x8*>(&Qf[((size_t)(tg * 4 + kk) * 64 + lane) * 8]);

  const unsigned short* Kb0 = Kf + (size_t)b * 524288;
  const unsigned short* Vb0 = Vf + (size_t)b * 524288;

  const f32x4 fz = {0.f, 0.f, 0.f, 0.f};
  const float FM2 = 17.312340f;
  const float NEG = -1.0e30f;
  f32x4 o[8];
#pragma unroll
  for (int nt = 0; nt < 8; ++nt) o[nt] = fz;
  float lrun[4] = {0.f, 0.f, 0.f, 0.f};

#pragma unroll
  for (int it = 0; it < 4; ++it) {
    if (it) __syncthreads();
    const unsigned short* Ksrc = Kb0 + (size_t)(c * 16 + it * 4) * 2048;
    const unsigned short* Vsrc = Vb0 + (size_t)(c * 8 + it * 2) * 4096;
#pragma unroll
    for (int j = 0; j < 2; ++j) {
      int off = (tid + j * 512) * 8;
      *reinterpret_cast<int4*>(&Kst[off]) = *reinterpret_cast<const int4*>(&Ksrc[off]);
      *reinterpret_cast<int4*>(&Vst[off]) = *reinterpret_cast<const int4*>(&Vsrc[off]);
    }
    __syncthreads();

    const int kv0 = c * 256 + it * 64;
    if (kv0 <= qbw + 15) {
      f32x4 sa[4];
#pragma unroll
      for (int Tl = 0; Tl < 4; ++Tl) {
        sa[Tl] = fz;
        bf16x8 kf[4];
#pragma unroll
        for (int kk = 0; kk < 4; ++kk)
          kf[kk] = *reinterpret_cast<const bf16x8*>(&Kst[((Tl * 4 + kk) * 64 + lane) * 8]);
#pragma unroll
        for (int kk = 0; kk < 4; ++kk)
          sa[Tl] = __builtin_amdgcn_mfma_f32_16x16x32_bf16(qf[kk], kf[kk], sa[Tl], 0, 0, 0);
      }

      const bool need_mask = (kv0 + 63 > qbw);
      float pv[4][4];
#pragma unroll
      for (int i = 0; i < 4; ++i) {
        float v0 = sa[0][i], v1 = sa[1][i], v2 = sa[2][i], v3 = sa[3][i];
        if (need_mask) {
          int qrow = qbw + g * 4 + i;
          if (kv0 + c16 > qrow) v0 = NEG;
          if (kv0 + 16 + c16 > qrow) v1 = NEG;
          if (kv0 + 32 + c16 > qrow) v2 = NEG;
          if (kv0 + 48 + c16 > qrow) v3 = NEG;
        }
        float p0 = exp2f(v0 - FM2);
        float p1 = exp2f(v1 - FM2);
        float p2 = exp2f(v2 - FM2);
        float p3 = exp2f(v3 - FM2);
        lrun[i] += (p0 + p1) + (p2 + p3);
        pv[0][i] = p0; pv[1][i] = p1; pv[2][i] = p2; pv[3][i] = p3;
      }
      unsigned int* Psw = &Psd[wid][0][0];
#pragma unroll
      for (int i = 0; i < 4; ++i) {
        Psw[(4 * g + i) * 36 + c16] = pack2bf(pv[0][i], pv[1][i]);
        Psw[(4 * g + i) * 36 + 16 + c16] = pack2bf(pv[2][i], pv[3][i]);
      }
      bf16x8 pf0 = *reinterpret_cast<const bf16x8*>(&Psw[c16 * 36 + 4 * g]);
      bf16x8 pf1 = *reinterpret_cast<const bf16x8*>(&Psw[c16 * 36 + 16 + 4 * g]);
#pragma unroll
      for (int nt = 0; nt < 8; ++nt) {
        bf16x8 vf = *reinterpret_cast<const bf16x8*>(&Vst[(nt * 64 + lane) * 8]);
        o[nt] = __builtin_amdgcn_mfma_f32_16x16x32_bf16(pf0, vf, o[nt], 0, 0, 0);
      }
#pragma unroll
      for (int nt = 0; nt < 8; ++nt) {
        bf16x8 vf = *reinterpret_cast<const bf16x8*>(&Vst[((8 + nt) * 64 + lane) * 8]);
        o[nt] = __builtin_amdgcn_mfma_f32_16x16x32_bf16(pf1, vf, o[nt], 0, 0, 0);
      }
    }
  }

#pragma unroll
  for (int i = 0; i < 4; ++i) {
    float l = lrun[i];
#pragma unroll
    for (int msk = 1; msk <= 8; msk <<= 1) l += __shfl_xor(l, msk);
    lrun[i] = l;
  }
  if (c16 == 0) {
#pragma unroll
    for (int i = 0; i < 4; ++i)
      PartL[(size_t)idx * 128 + wid * 16 + g * 4 + i] = lrun[i];
  }
#pragma unroll
  for (int qd = 0; qd < 4; ++qd)
#pragma unroll
    for (int i = 0; i < 4; ++i)
      PartO[(size_t)idx * 8192 + (wid * 16 + g * 4 + i) * 64 + qd * 16 + c16] =
          pack2bf(o[2 * qd][i], o[2 * qd + 1][i]);
}

// ---------------------------------------------------------------------------
// Kernel 3: combine partials (unchanged from R13).
// ---------------------------------------------------------------------------
__global__ __launch_bounds__(512) void combine_kernel(
    const unsigned int* __restrict__ PartO, const float* __restrict__ PartL,
    float* __restrict__ out) {
  const int bid = blockIdx.x;
  const int b = bid >> 7;
  const int sub = bid & 127;
  const int qb = sub >> 2;
  const int rq = sub & 3;
  const int tid = threadIdx.x;
  const int r = rq * 32 + (tid >> 4);
  const int dwb = (tid & 15) * 4;
  const int base = b * NPAIR + ((qb + 1) * (qb + 1)) / 4;
  const int nch = (qb + 2) >> 1;

  float accLo[4] = {0.f, 0.f, 0.f, 0.f};
  float accHi[4] = {0.f, 0.f, 0.f, 0.f};
  float l = 0.f;
  for (int c = 0; c < nch; ++c) {
    const int idx = base + c;
    l += PartL[(size_t)idx * 128 + r];
    const uint4 d = *reinterpret_cast<const uint4*>(
        &PartO[(size_t)idx * 8192 + r * 64 + dwb]);
    accLo[0] += bf2f((unsigned short)(d.x & 0xffff)); accHi[0] += bf2f((unsigned short)(d.x >> 16));
    accLo[1] += bf2f((unsigned short)(d.y & 0xffff)); accHi[1] += bf2f((unsigned short)(d.y >> 16));
    accLo[2] += bf2f((unsigned short)(d.z & 0xffff)); accHi[2] += bf2f((unsigned short)(d.z >> 16));
    accLo[3] += bf2f((unsigned short)(d.w & 0xffff)); accHi[3] += bf2f((unsigned short)(d.w >> 16));
  }
  const float inv = 1.0f / l;
  const size_t rowoff = ((size_t)b * Ss + qb * 128 + r) * Aa;
#pragma unroll
  for (int u = 0; u < 4; ++u) {
    int d = dwb + u;
    int colA = (d >> 4) * 32 + (d & 15);
    out[rowoff + colA] = rintf(accLo[u] * inv * 1e4f) * 1e-4f;
    out[rowoff + colA + 16] = rintf(accHi[u] * inv * 1e4f) * 1e-4f;
  }
}

// ---------------------------------------------------------------------------
extern "C" void kernel_launch(void* const* d_in, const int* in_sizes, int n_in,
                              void* d_out, int out_size, void* d_ws, size_t ws_size,
                              hipStream_t stream) {
  const float* X  = (const float*)d_in[0];
  const float* Wq = (const float*)d_in[1];
  const float* Wk = (const float*)d_in[2];
  const float* Wv = (const float*)d_in[3];
  float* out = (float*)d_out;

  unsigned char* ws = (unsigned char*)d_ws;
  unsigned short* Qf = (unsigned short*)(ws);                  // 4 MB fragment-major
  unsigned short* Kf = (unsigned short*)(ws + 4194304);        // 4 MB
  unsigned short* Vf = (unsigned short*)(ws + 8388608);        // 4 MB (kv-slot permuted)
  unsigned short* Wf = (unsigned short*)(ws + 12582912);       // 768 KB fragment-major
  unsigned int*  PartO = (unsigned int*)(ws + 13631488);       // 35.7 MB packed bf16
  float*         PartL = (float*)(ws + 49283072);              // 557 KB

  hipLaunchKernelGGL(wconv_kernel, dim3(192), dim3(256), 0, stream, Wq, Wk, Wv, Wf);
  hipLaunchKernelGGL(qkv_kernel, dim3(256, 3), dim3(256), 0, stream, X, Wf, Qf, Kf, Vf);
  hipLaunchKernelGGL(attn_kernel, dim3(1088), dim3(512), 0, stream, Qf, Kf, Vf, PartO, PartL);
  hipLaunchKernelGGL(combine_kernel, dim3(512), dim3(512), 0, stream, PartO, PartL, out);
}